// Round 2
// baseline (8559.341 us; speedup 1.0000x reference)
//
#include <hip/hip_runtime.h>
#include <hip/hip_bf16.h>

#define EPS_NORM 1e-12f
#define EPS_SM   1e-16f

__device__ __forceinline__ void atomAddF(float* p, float v) {
    unsafeAtomicAdd(p, v);   // global_atomic_add_f32 on gfx950 (coarse-grained mem)
}

// ---- h = relu(x @ W1 + b1); x[N,512], W1[512,16] -> h[N,16]
// block = 256 = 4 waves; 16 rows/block; each wave does 4 rows; lane = (rsub<<4)|c
__global__ __launch_bounds__(256) void k_gemm1(const float* __restrict__ x,
        const float* __restrict__ W1, const float* __restrict__ b1,
        float* __restrict__ h, int N) {
    __shared__ float w1t[16 * 516];          // transposed, pad 512->516: 2-way bank alias only
    int tid = threadIdx.x;
    for (int idx = tid; idx < 512 * 16; idx += 256) {
        int k = idx >> 4, c = idx & 15;
        w1t[c * 516 + k] = W1[idx];
    }
    __syncthreads();
    int wave = tid >> 6, lane = tid & 63;
    int c = lane & 15, rsub = lane >> 4;
    int row = blockIdx.x * 16 + wave * 4 + rsub;
    if (row >= N) return;
    const float4* xr = (const float4*)(x + (size_t)row * 512);
    const float4* wr = (const float4*)(w1t + c * 516);
    float acc = 0.f;
#pragma unroll 8
    for (int k4 = 0; k4 < 128; ++k4) {
        float4 xv = xr[k4];
        float4 wv = wr[k4];
        acc += xv.x * wv.x + xv.y * wv.y + xv.z * wv.z + xv.w * wv.w;
    }
    acc += b1[c];
    h[(size_t)row * 16 + c] = fmaxf(acc, 0.f);
}

// ---- per-node pre-pass: inv norm, self-loop weight, init denom s and output g
__global__ __launch_bounds__(256) void k_node_pre(const float* __restrict__ f,
        float* __restrict__ inv, float* __restrict__ pself, float* __restrict__ s,
        float* __restrict__ g, const float* __restrict__ beta, int N) {
    int i = blockIdx.x * 256 + threadIdx.x;
    if (i >= N) return;
    const float4* fr = (const float4*)(f + (size_t)i * 16);
    float4 a = fr[0], b = fr[1], c = fr[2], d = fr[3];
    float ss = a.x*a.x + a.y*a.y + a.z*a.z + a.w*a.w
             + b.x*b.x + b.y*b.y + b.z*b.z + b.w*b.w
             + c.x*c.x + c.y*c.y + c.z*c.z + c.w*c.w
             + d.x*d.x + d.y*d.y + d.z*d.z + d.w*d.w;
    float iv = 1.f / fmaxf(sqrtf(ss), EPS_NORM);
    float dself = ss * iv * iv;                    // == <xn_i, xn_i>
    float p = __expf(beta[0] * dself);
    inv[i] = iv;
    pself[i] = p;
    s[i] = p;                                      // denom starts with self-loop term
    float4 z = make_float4(0.f, 0.f, 0.f, 0.f);
    float4* gr = (float4*)(g + (size_t)i * 16);
    gr[0] = z; gr[1] = z; gr[2] = z; gr[3] = z;
}

// ---- edge pass 1: p = exp(beta * cos_sim), accumulate softmax denominator
__global__ __launch_bounds__(256) void k_edge1(const float* __restrict__ f,
        const float* __restrict__ inv, const int* __restrict__ src,
        const int* __restrict__ dst, float* __restrict__ pbuf, float* __restrict__ s,
        const float* __restrict__ beta, int E) {
    int e = blockIdx.x * 256 + threadIdx.x;
    if (e >= E) return;
    int si = src[e], di = dst[e];
    const float4* fs = (const float4*)(f + (size_t)si * 16);
    const float4* fd = (const float4*)(f + (size_t)di * 16);
    float4 u0 = fs[0], u1 = fs[1], u2 = fs[2], u3 = fs[3];
    float4 v0 = fd[0], v1 = fd[1], v2 = fd[2], v3 = fd[3];
    float dot = u0.x*v0.x + u0.y*v0.y + u0.z*v0.z + u0.w*v0.w
              + u1.x*v1.x + u1.y*v1.y + u1.z*v1.z + u1.w*v1.w
              + u2.x*v2.x + u2.y*v2.y + u2.z*v2.z + u2.w*v2.w
              + u3.x*v3.x + u3.y*v3.y + u3.z*v3.z + u3.w*v3.w;
    float p = __expf(beta[0] * dot * inv[si] * inv[di]);
    pbuf[e] = p;
    atomAddF(&s[di], p);
}

// ---- edge pass 2: a = p/(s+eps); g[dst] += a * f[src]
__global__ __launch_bounds__(256) void k_edge2(const float* __restrict__ f,
        const int* __restrict__ src, const int* __restrict__ dst,
        const float* __restrict__ pbuf, const float* __restrict__ s,
        float* __restrict__ g, int E) {
    int e = blockIdx.x * 256 + threadIdx.x;
    if (e >= E) return;
    int si = src[e], di = dst[e];
    float a = pbuf[e] / (s[di] + EPS_SM);
    const float4* fs = (const float4*)(f + (size_t)si * 16);
    float* gd = g + (size_t)di * 16;
    float4 u0 = fs[0], u1 = fs[1], u2 = fs[2], u3 = fs[3];
    atomAddF(gd + 0,  a * u0.x); atomAddF(gd + 1,  a * u0.y);
    atomAddF(gd + 2,  a * u0.z); atomAddF(gd + 3,  a * u0.w);
    atomAddF(gd + 4,  a * u1.x); atomAddF(gd + 5,  a * u1.y);
    atomAddF(gd + 6,  a * u1.z); atomAddF(gd + 7,  a * u1.w);
    atomAddF(gd + 8,  a * u2.x); atomAddF(gd + 9,  a * u2.y);
    atomAddF(gd + 10, a * u2.z); atomAddF(gd + 11, a * u2.w);
    atomAddF(gd + 12, a * u3.x); atomAddF(gd + 13, a * u3.y);
    atomAddF(gd + 14, a * u3.z); atomAddF(gd + 15, a * u3.w);
}

// ---- self-loop contribution: g[i] += (pself/(s+eps)) * f[i]  (thread per element)
__global__ __launch_bounds__(256) void k_node_post(const float* __restrict__ f,
        const float* __restrict__ pself, const float* __restrict__ s,
        float* __restrict__ g, int N) {
    int t = blockIdx.x * 256 + threadIdx.x;
    int i = t >> 4, k = t & 15;
    if (i >= N) return;
    float a = pself[i] / (s[i] + EPS_SM);
    g[(size_t)i * 16 + k] += a * f[(size_t)i * 16 + k];
}

// ---- out = softmax(f @ W2 + b2); f[N,16], W2[16,40]
__global__ __launch_bounds__(256) void k_out(const float* __restrict__ f,
        const float* __restrict__ W2, const float* __restrict__ b2,
        float* __restrict__ out, int N) {
    __shared__ float w2s[16 * 40];
    __shared__ float b2s[40];
    for (int idx = threadIdx.x; idx < 16 * 40; idx += 256) w2s[idx] = W2[idx];
    if (threadIdx.x < 40) b2s[threadIdx.x] = b2[threadIdx.x];
    __syncthreads();
    int i = blockIdx.x * 256 + threadIdx.x;
    if (i >= N) return;
    const float4* fr = (const float4*)(f + (size_t)i * 16);
    float4 q0 = fr[0], q1 = fr[1], q2 = fr[2], q3 = fr[3];
    float fv[16] = {q0.x, q0.y, q0.z, q0.w, q1.x, q1.y, q1.z, q1.w,
                    q2.x, q2.y, q2.z, q2.w, q3.x, q3.y, q3.z, q3.w};
    float z[40];
#pragma unroll
    for (int c = 0; c < 40; ++c) z[c] = b2s[c];
#pragma unroll
    for (int k = 0; k < 16; ++k) {
        float fk = fv[k];
#pragma unroll
        for (int c = 0; c < 40; ++c) z[c] += fk * w2s[k * 40 + c];
    }
    float m = z[0];
#pragma unroll
    for (int c = 1; c < 40; ++c) m = fmaxf(m, z[c]);
    float ssum = 0.f;
#pragma unroll
    for (int c = 0; c < 40; ++c) { z[c] = __expf(z[c] - m); ssum += z[c]; }
    float is = 1.f / ssum;
    float* orow = out + (size_t)i * 40;
#pragma unroll
    for (int c = 0; c < 40; ++c) orow[c] = z[c] * is;
}

extern "C" void kernel_launch(void* const* d_in, const int* in_sizes, int n_in,
                              void* d_out, int out_size, void* d_ws, size_t ws_size,
                              hipStream_t stream) {
    const float* x    = (const float*)d_in[0];
    const int*   eidx = (const int*)d_in[1];      // harness pushes integer inputs as int32
    const float* W1   = (const float*)d_in[2];
    const float* b1   = (const float*)d_in[3];
    const float* beta[3] = {(const float*)d_in[4], (const float*)d_in[5],
                            (const float*)d_in[6]};
    const float* W2   = (const float*)d_in[7];
    const float* b2   = (const float*)d_in[8];
    float*       out  = (float*)d_out;

    const int FIN = 512, H = 16;
    int N = in_sizes[0] / FIN;
    int E = in_sizes[1] / 2;

    const int* src = eidx;          // edge_index[0]
    const int* dst = eidx + E;      // edge_index[1]

    // workspace layout (floats): f0[N*16] f1[N*16] invb[N] pself[N] sden[N] pbuf[E]
    size_t nfeat = (size_t)N * H;
    float* f0    = (float*)d_ws;
    float* f1    = f0 + nfeat;
    float* invb  = f1 + nfeat;
    float* pself = invb + N;
    float* sden  = pself + N;
    float* pbuf  = sden + N;

    k_gemm1<<<dim3((N + 15) / 16), dim3(256), 0, stream>>>(x, W1, b1, f0, N);

    float* fin = f0;
    float* fout = f1;
    for (int l = 0; l < 3; ++l) {
        k_node_pre<<<dim3((N + 255) / 256), dim3(256), 0, stream>>>(
            fin, invb, pself, sden, fout, beta[l], N);
        k_edge1<<<dim3((E + 255) / 256), dim3(256), 0, stream>>>(
            fin, invb, src, dst, pbuf, sden, beta[l], E);
        k_edge2<<<dim3((E + 255) / 256), dim3(256), 0, stream>>>(
            fin, src, dst, pbuf, sden, fout, E);
        k_node_post<<<dim3((N * 16 + 255) / 256), dim3(256), 0, stream>>>(
            fin, pself, sden, fout, N);
        float* t = fin; fin = fout; fout = t;
    }
    k_out<<<dim3((N + 255) / 256), dim3(256), 0, stream>>>(fin, W2, b2, out, N);
}

// Round 3
// 723.128 us; speedup vs baseline: 11.8365x; 11.8365x over previous
//
#include <hip/hip_runtime.h>
#include <hip/hip_bf16.h>

#define EPS_NORM 1e-12f
#define EPS_SM   1e-16f

// ======================= CSR build =======================

__global__ __launch_bounds__(256) void k_deg(const int* __restrict__ dst,
        int* __restrict__ deg, int E) {
    int e = blockIdx.x * 256 + threadIdx.x;
    if (e < E) atomicAdd(&deg[dst[e]], 1);
}

// block-level exclusive scan over 1024-element tiles (Hillis-Steele in LDS)
__global__ __launch_bounds__(1024) void k_scan_block(const int* __restrict__ deg,
        int* __restrict__ offs, int* __restrict__ partial, int N) {
    __shared__ int sm[1024];
    int t = threadIdx.x;
    int g = blockIdx.x * 1024 + t;
    int v = (g < N) ? deg[g] : 0;
    sm[t] = v;
    __syncthreads();
    for (int d = 1; d < 1024; d <<= 1) {
        int tv = (t >= d) ? sm[t - d] : 0;
        __syncthreads();
        sm[t] += tv;
        __syncthreads();
    }
    if (g < N) offs[g] = sm[t] - v;                 // exclusive
    if (t == 1023) partial[blockIdx.x] = sm[1023];  // block total
}

__global__ void k_scan_partial(int* __restrict__ partial, int nb) {
    if (threadIdx.x == 0 && blockIdx.x == 0) {
        int run = 0;
        for (int i = 0; i < nb; ++i) { int t = partial[i]; partial[i] = run; run += t; }
    }
}

__global__ __launch_bounds__(256) void k_add_off(int* __restrict__ offs,
        const int* __restrict__ partial, int N) {
    int g = blockIdx.x * 256 + threadIdx.x;
    if (g < N) offs[g] += partial[g >> 10];
}

__global__ __launch_bounds__(256) void k_fill(const int* __restrict__ src,
        const int* __restrict__ dst, const int* __restrict__ offs,
        int* __restrict__ cur, int* __restrict__ csr, int E) {
    int e = blockIdx.x * 256 + threadIdx.x;
    if (e >= E) return;
    int d = dst[e];
    int pos = atomicAdd(&cur[d], 1);
    csr[offs[d] + pos] = src[e];
}

// ======================= h = relu(x @ W1 + b1), + inv-norm of h =======================
// block = 256 = 4 waves; 16 rows/block; lane = (rsub<<4)|c ; 16-lane group = one row
__global__ __launch_bounds__(256) void k_gemm1(const float* __restrict__ x,
        const float* __restrict__ W1, const float* __restrict__ b1,
        float* __restrict__ h, float* __restrict__ invn, int N) {
    __shared__ float w1t[16 * 516];          // transposed, pad 512->516 (2-way alias = free)
    int tid = threadIdx.x;
    for (int idx = tid; idx < 512 * 16; idx += 256) {
        int k = idx >> 4, c = idx & 15;
        w1t[c * 516 + k] = W1[idx];
    }
    __syncthreads();
    int wave = tid >> 6, lane = tid & 63;
    int c = lane & 15, rsub = lane >> 4;
    int row = blockIdx.x * 16 + wave * 4 + rsub;
    if (row >= N) return;
    const float4* xr = (const float4*)(x + (size_t)row * 512);
    const float4* wr = (const float4*)(w1t + c * 516);
    float acc = 0.f;
#pragma unroll 8
    for (int k4 = 0; k4 < 128; ++k4) {
        float4 xv = xr[k4];
        float4 wv = wr[k4];
        acc += xv.x * wv.x + xv.y * wv.y + xv.z * wv.z + xv.w * wv.w;
    }
    acc += b1[c];
    float val = fmaxf(acc, 0.f);
    h[(size_t)row * 16 + c] = val;
    float ss = val * val;
    ss += __shfl_xor(ss, 1); ss += __shfl_xor(ss, 2);
    ss += __shfl_xor(ss, 4); ss += __shfl_xor(ss, 8);
    if (c == 0) invn[row] = 1.f / fmaxf(sqrtf(ss), EPS_NORM);
}

// ======================= fused AGNN layer (CSR gather, no atomics) =======================
// one wave per dst node; lane = (edge_slot g<<4) | feature k; 8 edges per iteration
__global__ __launch_bounds__(256) void k_agnn(const float* __restrict__ f,
        const float* __restrict__ inv, const int* __restrict__ offs,
        const int* __restrict__ deg, const int* __restrict__ csr,
        const float* __restrict__ beta, float* __restrict__ fout,
        float* __restrict__ invout, int N) {
    int wid = (blockIdx.x * 256 + threadIdx.x) >> 6;   // node id (uniform per wave)
    if (wid >= N) return;
    int lane = threadIdx.x & 63;
    int g = lane >> 4, k = lane & 15;

    float fd  = f[(size_t)wid * 16 + k];
    float ivd = inv[wid];
    float b   = beta[0];

    // self-loop weight: exp(b * <xn,xn>)
    float sd = fd * fd;
    sd += __shfl_xor(sd, 1); sd += __shfl_xor(sd, 2);
    sd += __shfl_xor(sd, 4); sd += __shfl_xor(sd, 8);
    float pself = __expf(b * sd * ivd * ivd);
    float bs = b * ivd;                       // fold dst inv-norm into the scale

    int start = offs[wid];
    int end   = start + deg[wid];

    float sacc = 0.f, gacc = 0.f;
    for (int e = start + g; e < end; e += 8) {     // this group's residues {g, g+4} mod 8
        int  e1 = e + 4;
        bool v1 = e1 < end;
        int  si0 = csr[e];
        int  si1 = v1 ? csr[e1] : si0;
        float a0 = f[(size_t)si0 * 16 + k];
        float a1 = f[(size_t)si1 * 16 + k];
        float iv0 = inv[si0];
        float iv1 = inv[si1];
        float d0 = a0 * fd, d1 = a1 * fd;
        d0 += __shfl_xor(d0, 1); d1 += __shfl_xor(d1, 1);
        d0 += __shfl_xor(d0, 2); d1 += __shfl_xor(d1, 2);
        d0 += __shfl_xor(d0, 4); d1 += __shfl_xor(d1, 4);
        d0 += __shfl_xor(d0, 8); d1 += __shfl_xor(d1, 8);
        float p0 = __expf(bs * iv0 * d0);
        float p1 = v1 ? __expf(bs * iv1 * d1) : 0.f;
        sacc += p0 + p1;
        gacc += p0 * a0 + p1 * a1;
    }
    // combine the 4 edge-slot groups (values uniform within each 16-lane group)
    sacc += __shfl_xor(sacc, 16); sacc += __shfl_xor(sacc, 32);
    gacc += __shfl_xor(gacc, 16); gacc += __shfl_xor(gacc, 32);

    float denom = sacc + pself + EPS_SM;
    float outk  = (gacc + pself * fd) / denom;

    // next layer's inverse norm from the freshly computed row
    float ss = outk * outk;
    ss += __shfl_xor(ss, 1); ss += __shfl_xor(ss, 2);
    ss += __shfl_xor(ss, 4); ss += __shfl_xor(ss, 8);

    if (g == 0) {
        fout[(size_t)wid * 16 + k] = outk;
        if (k == 0) invout[wid] = 1.f / fmaxf(sqrtf(ss), EPS_NORM);
    }
}

// ======================= out = softmax(f @ W2 + b2) =======================
__global__ __launch_bounds__(256) void k_out(const float* __restrict__ f,
        const float* __restrict__ W2, const float* __restrict__ b2,
        float* __restrict__ out, int N) {
    __shared__ float w2s[16 * 40];
    __shared__ float b2s[40];
    for (int idx = threadIdx.x; idx < 16 * 40; idx += 256) w2s[idx] = W2[idx];
    if (threadIdx.x < 40) b2s[threadIdx.x] = b2[threadIdx.x];
    __syncthreads();
    int i = blockIdx.x * 256 + threadIdx.x;
    if (i >= N) return;
    const float4* fr = (const float4*)(f + (size_t)i * 16);
    float4 q0 = fr[0], q1 = fr[1], q2 = fr[2], q3 = fr[3];
    float fv[16] = {q0.x, q0.y, q0.z, q0.w, q1.x, q1.y, q1.z, q1.w,
                    q2.x, q2.y, q2.z, q2.w, q3.x, q3.y, q3.z, q3.w};
    float z[40];
#pragma unroll
    for (int c = 0; c < 40; ++c) z[c] = b2s[c];
#pragma unroll
    for (int k = 0; k < 16; ++k) {
        float fk = fv[k];
#pragma unroll
        for (int c = 0; c < 40; ++c) z[c] += fk * w2s[k * 40 + c];
    }
    float m = z[0];
#pragma unroll
    for (int c = 1; c < 40; ++c) m = fmaxf(m, z[c]);
    float ssum = 0.f;
#pragma unroll
    for (int c = 0; c < 40; ++c) { z[c] = __expf(z[c] - m); ssum += z[c]; }
    float is = 1.f / ssum;
    float* orow = out + (size_t)i * 40;
#pragma unroll
    for (int c = 0; c < 40; ++c) orow[c] = z[c] * is;
}

extern "C" void kernel_launch(void* const* d_in, const int* in_sizes, int n_in,
                              void* d_out, int out_size, void* d_ws, size_t ws_size,
                              hipStream_t stream) {
    const float* x    = (const float*)d_in[0];
    const int*   eidx = (const int*)d_in[1];      // harness pushes integer inputs as int32
    const float* W1   = (const float*)d_in[2];
    const float* b1   = (const float*)d_in[3];
    const float* beta[3] = {(const float*)d_in[4], (const float*)d_in[5],
                            (const float*)d_in[6]};
    const float* W2   = (const float*)d_in[7];
    const float* b2   = (const float*)d_in[8];
    float*       out  = (float*)d_out;

    const int FIN = 512, H = 16;
    int N = in_sizes[0] / FIN;
    int E = in_sizes[1] / 2;

    const int* src = eidx;          // edge_index[0]
    const int* dst = eidx + E;      // edge_index[1]

    // workspace layout
    size_t nfeat = (size_t)N * H;
    float* f0      = (float*)d_ws;          // N*16
    float* f1      = f0 + nfeat;            // N*16
    float* inv0    = f1 + nfeat;            // N
    float* inv1    = inv0 + N;              // N
    int*   offs    = (int*)(inv1 + N);      // N
    int*   degb    = offs + N;              // N
    int*   curb    = degb + N;              // N
    int*   partial = curb + N;              // 128
    int*   csr     = partial + 128;         // E

    int nb = (N + 1023) / 1024;

    // ---- CSR build (once per launch; same graph for all 3 layers)
    hipMemsetAsync(degb, 0, (size_t)N * 4, stream);
    hipMemsetAsync(curb, 0, (size_t)N * 4, stream);
    k_deg<<<dim3((E + 255) / 256), dim3(256), 0, stream>>>(dst, degb, E);
    k_scan_block<<<dim3(nb), dim3(1024), 0, stream>>>(degb, offs, partial, N);
    k_scan_partial<<<dim3(1), dim3(64), 0, stream>>>(partial, nb);
    k_add_off<<<dim3((N + 255) / 256), dim3(256), 0, stream>>>(offs, partial, N);
    k_fill<<<dim3((E + 255) / 256), dim3(256), 0, stream>>>(src, dst, offs, curb, csr, E);

    // ---- MLP in + 3 fused AGNN layers + MLP out
    k_gemm1<<<dim3((N + 15) / 16), dim3(256), 0, stream>>>(x, W1, b1, f0, inv0, N);

    float* fin = f0;  float* fout = f1;
    float* ivi = inv0; float* ivo = inv1;
    for (int l = 0; l < 3; ++l) {
        k_agnn<<<dim3((N + 3) / 4), dim3(256), 0, stream>>>(
            fin, ivi, offs, degb, csr, beta[l], fout, ivo, N);
        float* t = fin; fin = fout; fout = t;
        t = ivi; ivi = ivo; ivo = t;
    }
    k_out<<<dim3((N + 255) / 256), dim3(256), 0, stream>>>(fin, W2, b2, out, N);
}

// Round 4
// 616.959 us; speedup vs baseline: 13.8734x; 1.1721x over previous
//
#include <hip/hip_runtime.h>
#include <hip/hip_bf16.h>

#define EPS_NORM 1e-12f
#define EPS_SM   1e-16f

// ======================= CSR build =======================

// one atomic edge pass: position within dst segment + degree histogram for free
__global__ __launch_bounds__(256) void k_pos(const int* __restrict__ dst,
        int* __restrict__ deg, int* __restrict__ epos, int E) {
    int e = blockIdx.x * 256 + threadIdx.x;
    if (e >= E) return;
    int d = __builtin_nontemporal_load(&dst[e]);
    epos[e] = atomicAdd(&deg[d], 1);
}

// block-level exclusive scan over 1024-element tiles (Hillis-Steele in LDS)
__global__ __launch_bounds__(1024) void k_scan_block(const int* __restrict__ deg,
        int* __restrict__ offs, int* __restrict__ partial, int N) {
    __shared__ int sm[1024];
    int t = threadIdx.x;
    int g = blockIdx.x * 1024 + t;
    int v = (g < N) ? deg[g] : 0;
    sm[t] = v;
    __syncthreads();
    for (int d = 1; d < 1024; d <<= 1) {
        int tv = (t >= d) ? sm[t - d] : 0;
        __syncthreads();
        sm[t] += tv;
        __syncthreads();
    }
    if (g < N) offs[g] = sm[t] - v;                 // exclusive
    if (t == 1023) partial[blockIdx.x] = sm[1023];  // block total
}

// parallel exclusive scan of up to 128 block totals (single block)
__global__ __launch_bounds__(128) void k_scan_partial(int* __restrict__ partial, int nb) {
    __shared__ int sm[128];
    int t = threadIdx.x;
    int v = (t < nb) ? partial[t] : 0;
    sm[t] = v;
    __syncthreads();
    for (int d = 1; d < 128; d <<= 1) {
        int tv = (t >= d) ? sm[t - d] : 0;
        __syncthreads();
        sm[t] += tv;
        __syncthreads();
    }
    if (t < nb) partial[t] = sm[t] - v;             // exclusive
}

__global__ __launch_bounds__(256) void k_add_off(int* __restrict__ offs,
        const int* __restrict__ partial, int N, int E) {
    int g = blockIdx.x * 256 + threadIdx.x;
    if (g < N) offs[g] += partial[g >> 10];
    if (g == 0) offs[N] = E;                        // sentinel for last segment
}

// scatter without atomics; nt store (no line merging happens anyway — round-3 PMC)
__global__ __launch_bounds__(256) void k_fill(const int* __restrict__ src,
        const int* __restrict__ dst, const int* __restrict__ epos,
        const int* __restrict__ offs, int* __restrict__ csr, int E) {
    int e = blockIdx.x * 256 + threadIdx.x;
    if (e >= E) return;
    int d = __builtin_nontemporal_load(&dst[e]);
    int s = __builtin_nontemporal_load(&src[e]);
    int p = __builtin_nontemporal_load(&epos[e]);
    __builtin_nontemporal_store(s, &csr[offs[d] + p]);
}

// ======================= h = relu(x @ W1 + b1), + inv-norm of h =======================
// block = 256 = 4 waves; 16 rows/block; lane = (rsub<<4)|c ; 16-lane group = one row
__global__ __launch_bounds__(256) void k_gemm1(const float* __restrict__ x,
        const float* __restrict__ W1, const float* __restrict__ b1,
        float* __restrict__ h, float* __restrict__ invn, int N) {
    __shared__ float w1t[16 * 516];          // transposed, pad 512->516 (2-way alias = free)
    int tid = threadIdx.x;
    for (int idx = tid; idx < 512 * 16; idx += 256) {
        int k = idx >> 4, c = idx & 15;
        w1t[c * 516 + k] = W1[idx];
    }
    __syncthreads();
    int wave = tid >> 6, lane = tid & 63;
    int c = lane & 15, rsub = lane >> 4;
    int row = blockIdx.x * 16 + wave * 4 + rsub;
    if (row >= N) return;
    const float4* xr = (const float4*)(x + (size_t)row * 512);
    const float4* wr = (const float4*)(w1t + c * 516);
    float acc = 0.f;
#pragma unroll 8
    for (int k4 = 0; k4 < 128; ++k4) {
        float4 xv = xr[k4];
        float4 wv = wr[k4];
        acc += xv.x * wv.x + xv.y * wv.y + xv.z * wv.z + xv.w * wv.w;
    }
    acc += b1[c];
    float val = fmaxf(acc, 0.f);
    h[(size_t)row * 16 + c] = val;
    float ss = val * val;
    ss += __shfl_xor(ss, 1); ss += __shfl_xor(ss, 2);
    ss += __shfl_xor(ss, 4); ss += __shfl_xor(ss, 8);
    if (c == 0) invn[row] = 1.f / fmaxf(sqrtf(ss), EPS_NORM);
}

// ======================= fused AGNN layer (CSR gather, no atomics) =======================
// one wave per dst node; lane = (edge_slot g<<4) | feature k; 8 edges per iteration
__global__ __launch_bounds__(256) void k_agnn(const float* __restrict__ f,
        const float* __restrict__ inv, const int* __restrict__ offs,
        const int* __restrict__ csr, const float* __restrict__ beta,
        float* __restrict__ fout, float* __restrict__ invout, int N) {
    int wid = (blockIdx.x * 256 + threadIdx.x) >> 6;   // node id (uniform per wave)
    if (wid >= N) return;
    int lane = threadIdx.x & 63;
    int g = lane >> 4, k = lane & 15;

    float fd  = f[(size_t)wid * 16 + k];
    float ivd = inv[wid];
    float b   = beta[0];

    // self-loop weight: exp(b * <xn,xn>)
    float sd = fd * fd;
    sd += __shfl_xor(sd, 1); sd += __shfl_xor(sd, 2);
    sd += __shfl_xor(sd, 4); sd += __shfl_xor(sd, 8);
    float pself = __expf(b * sd * ivd * ivd);
    float bs = b * ivd;                       // fold dst inv-norm into the scale

    int start = offs[wid];
    int end   = offs[wid + 1];

    float sacc = 0.f, gacc = 0.f;
    for (int e = start + g; e < end; e += 8) {     // this group's residues {g, g+4} mod 8
        int  e1 = e + 4;
        bool v1 = e1 < end;
        int  si0 = csr[e];
        int  si1 = v1 ? csr[e1] : si0;
        float a0 = f[(size_t)si0 * 16 + k];
        float a1 = f[(size_t)si1 * 16 + k];
        float iv0 = inv[si0];
        float iv1 = inv[si1];
        float d0 = a0 * fd, d1 = a1 * fd;
        d0 += __shfl_xor(d0, 1); d1 += __shfl_xor(d1, 1);
        d0 += __shfl_xor(d0, 2); d1 += __shfl_xor(d1, 2);
        d0 += __shfl_xor(d0, 4); d1 += __shfl_xor(d1, 4);
        d0 += __shfl_xor(d0, 8); d1 += __shfl_xor(d1, 8);
        float p0 = __expf(bs * iv0 * d0);
        float p1 = v1 ? __expf(bs * iv1 * d1) : 0.f;
        sacc += p0 + p1;
        gacc += p0 * a0 + p1 * a1;
    }
    // combine the 4 edge-slot groups (values uniform within each 16-lane group)
    sacc += __shfl_xor(sacc, 16); sacc += __shfl_xor(sacc, 32);
    gacc += __shfl_xor(gacc, 16); gacc += __shfl_xor(gacc, 32);

    float denom = sacc + pself + EPS_SM;
    float outk  = (gacc + pself * fd) / denom;

    // next layer's inverse norm from the freshly computed row
    float ss = outk * outk;
    ss += __shfl_xor(ss, 1); ss += __shfl_xor(ss, 2);
    ss += __shfl_xor(ss, 4); ss += __shfl_xor(ss, 8);

    if (g == 0) {
        fout[(size_t)wid * 16 + k] = outk;
        if (k == 0) invout[wid] = 1.f / fmaxf(sqrtf(ss), EPS_NORM);
    }
}

// ======================= out = softmax(f @ W2 + b2) =======================
__global__ __launch_bounds__(256) void k_out(const float* __restrict__ f,
        const float* __restrict__ W2, const float* __restrict__ b2,
        float* __restrict__ out, int N) {
    __shared__ float w2s[16 * 40];
    __shared__ float b2s[40];
    for (int idx = threadIdx.x; idx < 16 * 40; idx += 256) w2s[idx] = W2[idx];
    if (threadIdx.x < 40) b2s[threadIdx.x] = b2[threadIdx.x];
    __syncthreads();
    int i = blockIdx.x * 256 + threadIdx.x;
    if (i >= N) return;
    const float4* fr = (const float4*)(f + (size_t)i * 16);
    float4 q0 = fr[0], q1 = fr[1], q2 = fr[2], q3 = fr[3];
    float fv[16] = {q0.x, q0.y, q0.z, q0.w, q1.x, q1.y, q1.z, q1.w,
                    q2.x, q2.y, q2.z, q2.w, q3.x, q3.y, q3.z, q3.w};
    float z[40];
#pragma unroll
    for (int c = 0; c < 40; ++c) z[c] = b2s[c];
#pragma unroll
    for (int k = 0; k < 16; ++k) {
        float fk = fv[k];
#pragma unroll
        for (int c = 0; c < 40; ++c) z[c] += fk * w2s[k * 40 + c];
    }
    float m = z[0];
#pragma unroll
    for (int c = 1; c < 40; ++c) m = fmaxf(m, z[c]);
    float ssum = 0.f;
#pragma unroll
    for (int c = 0; c < 40; ++c) { z[c] = __expf(z[c] - m); ssum += z[c]; }
    float is = 1.f / ssum;
    float* orow = out + (size_t)i * 40;
#pragma unroll
    for (int c = 0; c < 40; ++c) orow[c] = z[c] * is;
}

extern "C" void kernel_launch(void* const* d_in, const int* in_sizes, int n_in,
                              void* d_out, int out_size, void* d_ws, size_t ws_size,
                              hipStream_t stream) {
    const float* x    = (const float*)d_in[0];
    const int*   eidx = (const int*)d_in[1];      // harness pushes integer inputs as int32
    const float* W1   = (const float*)d_in[2];
    const float* b1   = (const float*)d_in[3];
    const float* beta[3] = {(const float*)d_in[4], (const float*)d_in[5],
                            (const float*)d_in[6]};
    const float* W2   = (const float*)d_in[7];
    const float* b2   = (const float*)d_in[8];
    float*       out  = (float*)d_out;

    const int FIN = 512, H = 16;
    int N = in_sizes[0] / FIN;
    int E = in_sizes[1] / 2;

    const int* src = eidx;          // edge_index[0]
    const int* dst = eidx + E;      // edge_index[1]

    // workspace layout
    size_t nfeat = (size_t)N * H;
    float* f0      = (float*)d_ws;          // N*16
    float* f1      = f0 + nfeat;            // N*16
    float* inv0    = f1 + nfeat;            // N
    float* inv1    = inv0 + N;              // N
    int*   offs    = (int*)(inv1 + N);      // N+1
    int*   degb    = offs + (N + 1);        // N
    int*   partial = degb + N;              // 128
    int*   epos    = partial + 128;         // E
    int*   csr     = epos + E;              // E

    int nb = (N + 1023) / 1024;

    // ---- CSR build (once per launch; same graph for all 3 layers)
    hipMemsetAsync(degb, 0, (size_t)N * 4, stream);
    k_pos<<<dim3((E + 255) / 256), dim3(256), 0, stream>>>(dst, degb, epos, E);
    k_scan_block<<<dim3(nb), dim3(1024), 0, stream>>>(degb, offs, partial, N);
    k_scan_partial<<<dim3(1), dim3(128), 0, stream>>>(partial, nb);
    k_add_off<<<dim3((N + 255) / 256), dim3(256), 0, stream>>>(offs, partial, N, E);
    k_fill<<<dim3((E + 255) / 256), dim3(256), 0, stream>>>(src, dst, epos, offs, csr, E);

    // ---- MLP in + 3 fused AGNN layers + MLP out
    k_gemm1<<<dim3((N + 15) / 16), dim3(256), 0, stream>>>(x, W1, b1, f0, inv0, N);

    float* fin = f0;  float* fout = f1;
    float* ivi = inv0; float* ivo = inv1;
    for (int l = 0; l < 3; ++l) {
        k_agnn<<<dim3((N + 3) / 4), dim3(256), 0, stream>>>(
            fin, ivi, offs, csr, beta[l], fout, ivo, N);
        float* t = fin; fin = fout; fout = t;
        t = ivi; ivi = ivo; ivo = t;
    }
    k_out<<<dim3((N + 255) / 256), dim3(256), 0, stream>>>(fin, W2, b2, out, N);
}